// Round 6
// baseline (95.276 us; speedup 1.0000x reference)
//
#include <hip/hip_runtime.h>
#include <hip/hip_bf16.h>
#include <cmath>

#define B_    4
#define C_    128
#define O_    128
#define K2T   9
#define CK    1152          // C_*K2T
#define NPIX  4096          // 64*64
#define VPITCH 296          // valbuf row pitch in bf16 (592B = 37*16B)

using bf16   = __bf16;
using bf16x4 = __attribute__((ext_vector_type(4))) __bf16;
using bf16x8 = __attribute__((ext_vector_type(8))) __bf16;
using f32x4  = __attribute__((ext_vector_type(4))) float;

// ws layout (bytes)  [total 2,138,112 <= 2,189,312 proven available in R1]:
//   [0, 294912)            w_bf   bf16[128*1152]   [o][cc*288 + k*32 + cq]
//   [294912, 368640)       wom_bf bf16[32*1152]    same order, rows 27..31 zero
//   [368640, 1548288)      pwh    uint2[4*9*4096]  4x f16 bilinear weights
//   [1548288, 2138112)     po     int[4*9*4096]    packed a00|dx|dy
#define WS_WBF 0
#define WS_WOM 294912
#define WS_PWH 368640
#define WS_PO  1548288

// ---------------- kernel R: repack weights (cc-major K order) ----------------
__global__ void __launch_bounds__(256) repack_kernel(
    const float* __restrict__ org_w, const float* __restrict__ offset_w,
    const float* __restrict__ mask_w, bf16* __restrict__ w_bf,
    bf16* __restrict__ wom_bf) {
  int t = blockIdx.x * 256 + threadIdx.x;   // 0 .. 160*1152-1
  if (t >= 160 * CK) return;
  int row = t / CK, r = t % CK;
  int cc = r / 288, rr = r % 288;
  int k = rr >> 5, cq = rr & 31;
  int c = cc * 32 + cq;
  if (row < 128) {
    w_bf[t] = (bf16)org_w[((size_t)row * C_ + c) * K2T + k];
  } else {
    int ch = row - 128;
    float v = 0.f;
    if (ch < 18)      v = offset_w[((size_t)ch * C_ + c) * K2T + k];
    else if (ch < 27) v = mask_w[((size_t)(ch - 18) * C_ + c) * K2T + k];
    wom_bf[(size_t)ch * CK + r] = (bf16)v;
  }
}

// -------- kernel 2: offset/mask conv (MFMA) + sampling params to global ------
__global__ void __launch_bounds__(576) offmask_params_kernel(
    const float* __restrict__ x, const bf16* __restrict__ wom_bf,
    const float* __restrict__ off_b, const float* __restrict__ mask_b,
    uint2* __restrict__ pwh, int* __restrict__ po) {
  __shared__ __align__(16) float xs3[32 * 192];       // 24,576 B
  __shared__ __align__(16) bf16  valbuf[64 * VPITCH]; // 37,888 B
  __shared__ __align__(16) float S_lds[32 * 64];      // 8,192 B

  int tid  = threadIdx.x;
  int bid0 = blockIdx.x;
  int bid  = (bid0 & 7) * 32 + (bid0 >> 3);  // XCD swizzle (bijective 256=8*32)
  int b    = bid >> 6, ho = bid & 63;
  int lane = tid & 63, wv = tid >> 6;        // 9 waves

  const float* xb = x + (size_t)b * C_ * NPIX;

  // ---- phase 1 (verbatim from R4, proven): S = wom * im2col, 32ch x 64px ----
  f32x4 acc1 = {};
  {
    int mf  = wv & 1, nfq = wv >> 1;
    const bf16* wbase1 = wom_bf + (size_t)(mf * 16 + (lane & 15)) * CK + (lane >> 4) * 8;
    const bf16* vbase1 = valbuf + (size_t)(nfq * 16 + (lane & 15)) * VPITCH + (lane >> 4) * 8;
    int p  = tid & 63;
    int g2 = tid >> 6;     // 0..8 (8 skips build)
    for (int cc = 0; cc < 4; ++cc) {
      __syncthreads();
#pragma unroll
      for (int i = 0; i < 3; ++i) {
        int slot = tid + i * 576;
        if (slot < 1536) {
          int ch = slot / 48, rem2 = slot % 48;
          int row = rem2 / 16, l16 = rem2 & 15;
          int y = ho - 1 + row;
          float4 v = make_float4(0.f, 0.f, 0.f, 0.f);
          if ((unsigned)y < 64u)
            v = *((const float4*)(xb + (size_t)(cc * 32 + ch) * NPIX + y * 64) + l16);
          *(float4*)(&xs3[ch * 192 + row * 64 + l16 * 4]) = v;
        }
      }
      __syncthreads();
      if (g2 < 8) {
#pragma unroll
        for (int k = 0; k < 9; ++k) {
          int ki = k / 3, kj = k % 3;
          int px = p - 1 + kj;
          bf16x4 pr;
#pragma unroll
          for (int cqi = 0; cqi < 4; ++cqi) {
            int cq = (g2 << 2) + cqi;
            float v = ((unsigned)px < 64u) ? xs3[cq * 192 + ki * 64 + px] : 0.f;
            pr[cqi] = (bf16)v;
          }
          *(bf16x4*)(valbuf + (size_t)p * VPITCH + k * 32 + (g2 << 2)) = pr;
        }
      }
      __syncthreads();
      if (wv < 8) {
#pragma unroll
        for (int ks = 0; ks < 9; ++ks) {
          bf16x8 a  = *(const bf16x8*)(wbase1 + cc * 288 + ks * 32);
          bf16x8 bv = *(const bf16x8*)(vbase1 + ks * 32);
          acc1 = __builtin_amdgcn_mfma_f32_16x16x32_bf16(a, bv, acc1, 0, 0, 0);
        }
      }
    }
  }
  __syncthreads();
  if (wv < 8) {
    int mf = wv & 1, nfq = wv >> 1;
    int so = mf * 16 + (lane >> 4) * 4;
    int sp = nfq * 16 + (lane & 15);
#pragma unroll
    for (int r = 0; r < 4; ++r) S_lds[(so + r) * 64 + sp] = acc1[r];
  }
  __syncthreads();

  // ---- params: entry (k=wv, p=lane), exact per-corner clamp ----
  {
    int k = tid >> 6, p = tid & 63;
    float dy = S_lds[(2 * k) * 64 + p]     + off_b[2 * k];
    float dx = S_lds[(2 * k + 1) * 64 + p] + off_b[2 * k + 1];
    float mz = S_lds[(18 + k) * 64 + p]    + mask_b[k];
    float m  = 1.f / (1.f + expf(-mz));
    int ki = k / 3, kj = k % 3;
    float py = (float)(ho - 1 + ki) + dy;
    float px = (float)(p  - 1 + kj) + dx;
    float fy = floorf(py), fx = floorf(px);
    int y0 = (int)fy, x0 = (int)fx;
    float wy = py - fy, wx = px - fx;
    float vy0 = ((unsigned)y0       < 64u) ? 1.f : 0.f;
    float vy1 = ((unsigned)(y0 + 1) < 64u) ? 1.f : 0.f;
    float vx0 = ((unsigned)x0       < 64u) ? 1.f : 0.f;
    float vx1 = ((unsigned)(x0 + 1) < 64u) ? 1.f : 0.f;
    int y0c = y0 < 0 ? 0 : (y0 > 63 ? 63 : y0);
    int y1c = y0 + 1 < 0 ? 0 : (y0 + 1 > 63 ? 63 : y0 + 1);
    int c0c = x0 < 0 ? 0 : (x0 > 63 ? 63 : x0);
    int c1c = x0 + 1 < 0 ? 0 : (x0 + 1 > 63 ? 63 : x0 + 1);
    float pw0 = (1.f - wy) * (1.f - wx) * m * vy0 * vx0;
    float pw1 = (1.f - wy) * wx         * m * vy0 * vx1;
    float pw2 = wy * (1.f - wx)         * m * vy1 * vx0;
    float pw3 = wy * wx                 * m * vy1 * vx1;
    int a00 = y0c * 64 + c0c;
    int dxb = c1c - c0c, dyb = y1c - y0c;   // each 0 or 1
    unsigned short h0 = __builtin_bit_cast(unsigned short, (_Float16)pw0);
    unsigned short h1 = __builtin_bit_cast(unsigned short, (_Float16)pw1);
    unsigned short h2 = __builtin_bit_cast(unsigned short, (_Float16)pw2);
    unsigned short h3 = __builtin_bit_cast(unsigned short, (_Float16)pw3);
    int idx = ((b * 9 + k) << 12) + ho * 64 + p;
    pwh[idx] = make_uint2((unsigned)h0 | ((unsigned)h1 << 16),
                          (unsigned)h2 | ((unsigned)h3 << 16));
    po[idx]  = a00 | (dxb << 12) | (dyb << 13);
  }
}

// -------- kernel 3: deformable conv — gather from L2, MFMA, no slab ---------
__global__ void __launch_bounds__(576, 5) deform_kernel(
    const float* __restrict__ x, const bf16* __restrict__ w_bf,
    const uint2* __restrict__ pwh, const int* __restrict__ po,
    float* __restrict__ out) {
  __shared__ __align__(16) bf16 valbuf[32 * VPITCH];  // 18,944 B

  int tid  = threadIdx.x;
  int bid0 = blockIdx.x;
  int bid  = (bid0 & 7) * 64 + (bid0 >> 3);  // XCD swizzle (bijective 512=8*64)
  int b    = bid >> 7;
  int rem  = bid & 127;
  int ho   = rem >> 1, ph = rem & 1;
  int lane = tid & 63, wv = tid >> 6;        // 9 waves

  const float* xb = x + (size_t)b * C_ * NPIX;

  // ---- per-thread sampling setup: entry (k, px) x 16-channel half ----
  int half = (tid >= 288) ? 1 : 0;
  int e    = tid - half * 288;               // 0..287
  int k    = e >> 5, px = e & 31;
  int pidx = ((b * 9 + k) << 12) + ho * 64 + ph * 32 + px;
  uint2 hp = pwh[pidx];
  int   pp = po[pidx];
  float pw0 = (float)__builtin_bit_cast(_Float16, (unsigned short)(hp.x & 0xFFFF));
  float pw1 = (float)__builtin_bit_cast(_Float16, (unsigned short)(hp.x >> 16));
  float pw2 = (float)__builtin_bit_cast(_Float16, (unsigned short)(hp.y & 0xFFFF));
  float pw3 = (float)__builtin_bit_cast(_Float16, (unsigned short)(hp.y >> 16));
  int a00 = pp & 0xFFF;
  int dxb = (pp >> 12) & 1, dyb = (pp >> 13) & 1;
  int a01 = a00 + dxb, a10 = a00 + dyb * 64, a11 = a00 + dxb + dyb * 64;
  int vb_off = px * VPITCH + k * 32 + half * 16;
  const float* cb0 = xb + (size_t)(half * 16) * NPIX;

  f32x4 acc[2] = {};
  const bf16* wbase = w_bf + (size_t)(wv * 16 + (lane & 15)) * CK + (lane >> 4) * 8;
  const bf16* vbase = valbuf + (size_t)(lane & 15) * VPITCH + (lane >> 4) * 8;

  for (int cc = 0; cc < 4; ++cc) {
    if (cc) __syncthreads();                 // prev MFMA done with valbuf
    // sample 16 channels straight from global (L1/L2)
    const float* cb = cb0 + (size_t)(cc * 32) * NPIX;
    bf16 tmp[16];
#pragma unroll
    for (int j = 0; j < 16; ++j) {
      const float* c_ = cb + (size_t)j * NPIX;
      float v = pw0 * c_[a00] + pw1 * c_[a01] + pw2 * c_[a10] + pw3 * c_[a11];
      tmp[j] = (bf16)v;
    }
    *(bf16x8*)(valbuf + vb_off)     = *(bf16x8*)&tmp[0];
    *(bf16x8*)(valbuf + vb_off + 8) = *(bf16x8*)&tmp[8];
    __syncthreads();                         // valbuf ready
    if (wv < 8) {
#pragma unroll
      for (int ks = 0; ks < 9; ++ks) {
        bf16x8 a0 = *(const bf16x8*)(wbase + cc * 288 + ks * 32);
#pragma unroll
        for (int nf = 0; nf < 2; ++nf) {
          bf16x8 bv = *(const bf16x8*)(vbase + (size_t)nf * 16 * VPITCH + ks * 32);
          acc[nf] = __builtin_amdgcn_mfma_f32_16x16x32_bf16(a0, bv, acc[nf], 0, 0, 0);
        }
      }
    }
  }

  // ---- epilogue: D row=(lane>>4)*4+r (=o), col=lane&15 (=px) ----
  if (wv < 8) {
    float* ob = out + (size_t)b * O_ * NPIX + ho * 64 + ph * 32;
#pragma unroll
    for (int nf = 0; nf < 2; ++nf)
#pragma unroll
      for (int r = 0; r < 4; ++r) {
        int o = wv * 16 + (lane >> 4) * 4 + r;
        int p2 = nf * 16 + (lane & 15);
        ob[(size_t)o * NPIX + p2] = acc[nf][r];
      }
  }
}

// ---------------- launch ----------------
extern "C" void kernel_launch(void* const* d_in, const int* in_sizes, int n_in,
                              void* d_out, int out_size, void* d_ws, size_t ws_size,
                              hipStream_t stream) {
  const float* x        = (const float*)d_in[0];
  const float* org_w    = (const float*)d_in[1];
  const float* offset_w = (const float*)d_in[2];
  const float* off_b    = (const float*)d_in[3];
  const float* mask_w   = (const float*)d_in[4];
  const float* mask_b   = (const float*)d_in[5];
  float* out = (float*)d_out;
  char*  ws  = (char*)d_ws;

  bf16*  w_bf   = (bf16*)(ws + WS_WBF);
  bf16*  wom_bf = (bf16*)(ws + WS_WOM);
  uint2* pwh    = (uint2*)(ws + WS_PWH);
  int*   po     = (int*)(ws + WS_PO);

  repack_kernel<<<720, 256, 0, stream>>>(org_w, offset_w, mask_w, w_bf, wom_bf);
  offmask_params_kernel<<<256, 576, 0, stream>>>(x, wom_bf, off_b, mask_b, pwh, po);
  deform_kernel<<<512, 576, 0, stream>>>(x, w_bf, pwh, po, out);
}

// Round 7
// 60.744 us; speedup vs baseline: 1.5685x; 1.5685x over previous
//
#include <hip/hip_runtime.h>
#include <hip/hip_bf16.h>
#include <cmath>

#define B_    4
#define C_    128
#define O_    128
#define K2T   9
#define CK    1152          // C_*K2T
#define NPIX  4096          // 64*64
#define VPITCH 296          // valbuf row pitch in bf16 (592B = 37*16B)
#define SLABW 768           // per-wave slab: 12 rows * 64 cols (floats)

using bf16   = __bf16;
using bf16x8 = __attribute__((ext_vector_type(8))) __bf16;
using f32x4  = __attribute__((ext_vector_type(4))) float;

// ws layout (bytes):
//   [0, 294912)        w_bf   bf16[128*1152]  K-reordered: [o][cc*288 + k*32 + cq]
//   [294912, 368640)   wom_bf bf16[32*1152]   same K order, rows 27..31 zero
#define WS_WBF 0
#define WS_WOM 294912

// ---------------- kernel R: repack weights (K-reordered) ----------------
__global__ void __launch_bounds__(256) repack_kernel(
    const float* __restrict__ org_w, const float* __restrict__ offset_w,
    const float* __restrict__ mask_w, bf16* __restrict__ w_bf,
    bf16* __restrict__ wom_bf) {
  int t = blockIdx.x * 256 + threadIdx.x;   // 0 .. 160*1152-1
  if (t >= 160 * CK) return;
  int row = t / CK, r = t % CK;
  int cc = r / 288, rr = r % 288;
  int k = rr >> 5, cq = rr & 31;
  int c = cc * 32 + cq;
  if (row < 128) {
    w_bf[t] = (bf16)org_w[((size_t)row * C_ + c) * K2T + k];
  } else {
    int ch = row - 128;
    float v = 0.f;
    if (ch < 18)      v = offset_w[((size_t)ch * C_ + c) * K2T + k];
    else if (ch < 27) v = mask_w[((size_t)(ch - 18) * C_ + c) * K2T + k];
    wom_bf[(size_t)ch * CK + r] = (bf16)v;
  }
}

__device__ __forceinline__ void gl_lds16(const float* src, float* lds_uniform) {
  __builtin_amdgcn_global_load_lds(
      (const __attribute__((address_space(1))) void*)src,
      (__attribute__((address_space(3))) void*)lds_uniform, 16, 0, 0);
}

// --------- fused kernel: per-wave-private pipelines, barriers at MFMA only ---
__global__ void __launch_bounds__(512) deform_fused_kernel(
    const float* __restrict__ x, const bf16* __restrict__ w_bf,
    const bf16* __restrict__ wom_bf, const float* __restrict__ off_b,
    const float* __restrict__ mask_b, float* __restrict__ out) {
  __shared__ __align__(16) float xslab[8 * 2 * SLABW];   // 49,152 B: per-wave dbuf
  __shared__ __align__(16) bf16  valbuf[64 * VPITCH];    // 37,888 B
  __shared__ __align__(16) float S_lds[32 * 64];         // 8,192 B

  int tid = threadIdx.x;
  int w   = tid >> 6, p = tid & 63;          // 8 waves, lane = pixel
  int bid0 = blockIdx.x;
  int bid  = (bid0 & 7) * 32 + (bid0 >> 3);  // XCD swizzle (bijective 256=8*32)
  int b    = bid >> 6, ho = bid & 63;

  const float* xb = x + (size_t)b * C_ * NPIX;

  // ================= PHASE 1: offset/mask conv (reg rows + shfl im2col) =====
  f32x4 acc1 = {};
  {
    int mf1 = w & 1, nf1 = w >> 1;
    const bf16* wb1 = wom_bf + (size_t)(mf1 * 16 + (p & 15)) * CK + (p >> 4) * 8;
    const bf16* vb1 = valbuf + (size_t)(nf1 * 16 + (p & 15)) * VPITCH + (p >> 4) * 8;
    float rows[2][3];
#pragma unroll
    for (int ki = 0; ki < 3; ++ki) {         // load ph=0 rows (ch = w)
      int y = ho - 1 + ki; y = y < 0 ? 0 : (y > 63 ? 63 : y);
      rows[0][ki] = xb[(size_t)w * NPIX + y * 64 + p];
    }
#pragma unroll
    for (int ph = 0; ph < 16; ++ph) {
      if (ph < 15) {                         // prefetch next channel's rows
        int ch = (ph + 1) * 8 + w;
#pragma unroll
        for (int ki = 0; ki < 3; ++ki) {
          int y = ho - 1 + ki; y = y < 0 ? 0 : (y > 63 ? 63 : y);
          rows[(ph + 1) & 1][ki] = xb[(size_t)ch * NPIX + y * 64 + p];
        }
      }
      {                                      // build im2col column for my ch
        int cq = ((ph & 3) << 3) + w;
        bf16* vb = valbuf + (size_t)p * VPITCH + cq;
#pragma unroll
        for (int k = 0; k < 9; ++k) {
          int ki = k / 3, kj = k % 3;
          int px = p - 1 + kj;
          bool okr = (unsigned)(ho - 1 + ki) < 64u;
          bool okx = (unsigned)px < 64u;
          float v = __shfl(rows[ph & 1][ki], okx ? px : 0);
          vb[k * 32] = (bf16)((okr && okx) ? v : 0.f);
        }
      }
      if ((ph & 3) == 3) {
        int cc = ph >> 2;
        asm volatile("s_waitcnt lgkmcnt(0)" ::: "memory");
        __builtin_amdgcn_s_barrier();
        __builtin_amdgcn_sched_barrier(0);
#pragma unroll
        for (int ks = 0; ks < 9; ++ks) {
          bf16x8 a  = *(const bf16x8*)(wb1 + cc * 288 + ks * 32);
          bf16x8 bv = *(const bf16x8*)(vb1 + ks * 32);
          acc1 = __builtin_amdgcn_mfma_f32_16x16x32_bf16(a, bv, acc1, 0, 0, 0);
        }
        asm volatile("s_waitcnt lgkmcnt(0)" ::: "memory");
        __builtin_amdgcn_s_barrier();
        __builtin_amdgcn_sched_barrier(0);
      }
    }
  }
  // S write: rows = offmask channel 0..31, cols = pixel
  {
    int so = (w & 1) * 16 + (p >> 4) * 4;
    int sp = (w >> 1) * 16 + (p & 15);
#pragma unroll
    for (int r = 0; r < 4; ++r) S_lds[(so + r) * 64 + sp] = acc1[r];
  }
  __syncthreads();

  int y_start = ho - 5; y_start = y_start < 0 ? 0 : (y_start > 52 ? 52 : y_start);
  float* myslab = xslab + w * (2 * SLABW);

  // prologue DMA for phase 0 (ch = w), before params compute (overlap)
  {
    const float* src = xb + (size_t)w * NPIX + y_start * 64 + p * 4;
#pragma unroll
    for (int j = 0; j < 3; ++j) gl_lds16(src + j * 256, myslab + j * 256);
  }

  // ---- sampling params for my pixel p, all 9 taps (exact clamp semantics) ---
  float pw[9][4];
  int   psa[9], pdx[9], pdy[9];
#pragma unroll
  for (int k = 0; k < 9; ++k) {
    float dy = S_lds[(2 * k) * 64 + p]     + off_b[2 * k];
    float dx = S_lds[(2 * k + 1) * 64 + p] + off_b[2 * k + 1];
    float mz = S_lds[(18 + k) * 64 + p]    + mask_b[k];
    float m  = 1.f / (1.f + expf(-mz));
    int ki = k / 3, kj = k % 3;
    float py = (float)(ho - 1 + ki) + dy;
    float px = (float)(p  - 1 + kj) + dx;
    float fy = floorf(py), fx = floorf(px);
    int y0 = (int)fy, x0 = (int)fx;
    float wy = py - fy, wx = px - fx;
    float vy0 = ((unsigned)y0       < 64u) ? 1.f : 0.f;
    float vy1 = ((unsigned)(y0 + 1) < 64u) ? 1.f : 0.f;
    float vx0 = ((unsigned)x0       < 64u) ? 1.f : 0.f;
    float vx1 = ((unsigned)(x0 + 1) < 64u) ? 1.f : 0.f;
    int y0c = y0 < 0 ? 0 : (y0 > 63 ? 63 : y0);
    int y1c = y0 + 1 < 0 ? 0 : (y0 + 1 > 63 ? 63 : y0 + 1);
    int c0c = x0 < 0 ? 0 : (x0 > 63 ? 63 : x0);
    int c1c = x0 + 1 < 0 ? 0 : (x0 + 1 > 63 ? 63 : x0 + 1);
    pw[k][0] = (1.f - wy) * (1.f - wx) * m * vy0 * vx0;
    pw[k][1] = (1.f - wy) * wx         * m * vy0 * vx1;
    pw[k][2] = wy * (1.f - wx)         * m * vy1 * vx0;
    pw[k][3] = wy * wx                 * m * vy1 * vx1;
    psa[k] = (y0c - y_start) * 64 + c0c;   // slab dword index, row-uniform map
    pdx[k] = c1c - c0c;                    // 0 or 1
    pdy[k] = y1c - y0c;                    // 0 or 1 (0 at y-edges)
  }

  // ================= PHASE 2: deformable conv (private pipelines) ==========
  f32x4 acc[2][2] = {};
  int mfr = 2 * (w & 3), nff = 2 * (w >> 2);
  const bf16* aB0 = w_bf + (size_t)((mfr    ) * 16 + (p & 15)) * CK + (p >> 4) * 8;
  const bf16* aB1 = w_bf + (size_t)((mfr + 1) * 16 + (p & 15)) * CK + (p >> 4) * 8;
  const bf16* vB0 = valbuf + (size_t)((nff    ) * 16 + (p & 15)) * VPITCH + (p >> 4) * 8;
  const bf16* vB1 = valbuf + (size_t)((nff + 1) * 16 + (p & 15)) * VPITCH + (p >> 4) * 8;

#pragma unroll
  for (int ph = 0; ph < 16; ++ph) {
    asm volatile("s_waitcnt vmcnt(0)" ::: "memory");  // my slab for ph landed
    __builtin_amdgcn_sched_barrier(0);                // keep reads below wait
    if (ph < 15) {                                    // DMA next channel
      int ch = (ph + 1) * 8 + w;
      const float* src = xb + (size_t)ch * NPIX + y_start * 64 + p * 4;
      float* dst = myslab + ((ph + 1) & 1) * SLABW;
#pragma unroll
      for (int j = 0; j < 3; ++j) gl_lds16(src + j * 256, dst + j * 256);
    }
    {   // sample my channel: 9 taps at my pixel p
      const float* sb = myslab + (ph & 1) * SLABW;
      int cq = ((ph & 3) << 3) + w;
      bf16* vb = valbuf + (size_t)p * VPITCH + cq;
#pragma unroll
      for (int k = 0; k < 9; ++k) {
        int sa = psa[k];
        float vA0 = sb[sa],          vA1 = sb[sa + 64];           // ds_read2
        float vB0s = sb[sa + pdx[k]], vB1s = sb[sa + pdx[k] + 64]; // ds_read2
        float v10 = pdy[k] ? vA1 : vA0;
        float v11 = pdy[k] ? vB1s : vB0s;
        float v = pw[k][0] * vA0 + pw[k][1] * vB0s + pw[k][2] * v10 + pw[k][3] * v11;
        vb[k * 32] = (bf16)v;
      }
    }
    if ((ph & 3) == 3) {
      int cc = ph >> 2;
      asm volatile("s_waitcnt lgkmcnt(0)" ::: "memory");  // my valbuf writes drained
      __builtin_amdgcn_s_barrier();
      __builtin_amdgcn_sched_barrier(0);
#pragma unroll
      for (int ks = 0; ks < 9; ++ks) {
        bf16x8 a0 = *(const bf16x8*)(aB0 + cc * 288 + ks * 32);
        bf16x8 a1 = *(const bf16x8*)(aB1 + cc * 288 + ks * 32);
        bf16x8 b0 = *(const bf16x8*)(vB0 + ks * 32);
        bf16x8 b1 = *(const bf16x8*)(vB1 + ks * 32);
        acc[0][0] = __builtin_amdgcn_mfma_f32_16x16x32_bf16(a0, b0, acc[0][0], 0, 0, 0);
        acc[0][1] = __builtin_amdgcn_mfma_f32_16x16x32_bf16(a0, b1, acc[0][1], 0, 0, 0);
        acc[1][0] = __builtin_amdgcn_mfma_f32_16x16x32_bf16(a1, b0, acc[1][0], 0, 0, 0);
        acc[1][1] = __builtin_amdgcn_mfma_f32_16x16x32_bf16(a1, b1, acc[1][1], 0, 0, 0);
      }
      asm volatile("s_waitcnt lgkmcnt(0)" ::: "memory");  // my B-reads done
      __builtin_amdgcn_s_barrier();                       // before overwrites
      __builtin_amdgcn_sched_barrier(0);
    }
  }

  // ---- epilogue: D row=(p>>4)*4+r (=o), col=p&15 (=px) ----
  {
    float* ob = out + (size_t)b * O_ * NPIX + ho * 64;
#pragma unroll
    for (int mi = 0; mi < 2; ++mi)
#pragma unroll
      for (int ni = 0; ni < 2; ++ni)
#pragma unroll
        for (int r = 0; r < 4; ++r) {
          int o  = (mfr + mi) * 16 + (p >> 4) * 4 + r;
          int px = (nff + ni) * 16 + (p & 15);
          ob[(size_t)o * NPIX + px] = acc[mi][ni][r];
        }
  }
}

// ---------------- launch ----------------
extern "C" void kernel_launch(void* const* d_in, const int* in_sizes, int n_in,
                              void* d_out, int out_size, void* d_ws, size_t ws_size,
                              hipStream_t stream) {
  const float* x        = (const float*)d_in[0];
  const float* org_w    = (const float*)d_in[1];
  const float* offset_w = (const float*)d_in[2];
  const float* off_b    = (const float*)d_in[3];
  const float* mask_w   = (const float*)d_in[4];
  const float* mask_b   = (const float*)d_in[5];
  float* out = (float*)d_out;
  char*  ws  = (char*)d_ws;

  bf16* w_bf   = (bf16*)(ws + WS_WBF);
  bf16* wom_bf = (bf16*)(ws + WS_WOM);

  repack_kernel<<<720, 256, 0, stream>>>(org_w, offset_w, mask_w, w_bf, wom_bf);
  deform_fused_kernel<<<256, 512, 0, stream>>>(x, w_bf, wom_bf, off_b, mask_b, out);
}